// Round 1
// baseline (61.776 us; speedup 1.0000x reference)
//
#include <hip/hip_runtime.h>
#include <hip/hip_bf16.h>

typedef __bf16 bf16_t;
typedef bf16_t bf16x8 __attribute__((ext_vector_type(8)));
typedef float f32x4 __attribute__((ext_vector_type(4)));

#define KD 768
#define BDIM 4096

// async global->LDS, 16B per lane; LDS dest must be wave-uniform base (+lane*16 implicit)
#define GLOAD_LDS16(gptr, lptr)                                             \
    __builtin_amdgcn_global_load_lds(                                       \
        (const __attribute__((address_space(1))) unsigned int*)(gptr),      \
        (__attribute__((address_space(3))) unsigned int*)(lptr), 16, 0, 0)

// ---------------- Kernel 1: row-normalize fp32 -> bf16 ----------------
__global__ __launch_bounds__(256) void normalize_rows(
    const float* __restrict__ x, __hip_bfloat16* __restrict__ xn)
{
    const int row = blockIdx.x;
    const int t = threadIdx.x;
    const float* xr = x + (long)row * KD;

    float v[3];
    float ss = 0.f;
#pragma unroll
    for (int i = 0; i < 3; ++i) {
        v[i] = xr[t + 256 * i];
        ss += v[i] * v[i];
    }
    // wave(64) reduce
#pragma unroll
    for (int off = 32; off > 0; off >>= 1) ss += __shfl_down(ss, off);
    __shared__ float wss[4];
    const int lane = t & 63, wv = t >> 6;
    if (lane == 0) wss[wv] = ss;
    __syncthreads();
    const float tot = wss[0] + wss[1] + wss[2] + wss[3];
    const float inv = 1.0f / fmaxf(sqrtf(tot), 1e-8f);
#pragma unroll
    for (int i = 0; i < 3; ++i)
        xn[(long)row * KD + t + 256 * i] = __float2bfloat16(v[i] * inv);
}

// ---------------- Kernel 2: sim = Xn @ Xn^T, fused Linear(1,2) epilogue ----------------
// m97 structure: 128x128 tile, BK=32, 4 waves (2x2), each wave 64x64 = 4x4 frags of 16x16.
__global__ __launch_bounds__(256) void sim_gemm(
    const bf16_t* __restrict__ Xn,
    const float* __restrict__ fcw, const float* __restrict__ fcb,
    float* __restrict__ out)
{
    __shared__ __align__(16) bf16_t As[128 * 32];  // 8 KB
    __shared__ __align__(16) bf16_t Bs[128 * 32];  // 8 KB

    const int tid  = threadIdx.x;
    const int wave = tid >> 6;
    const int lane = tid & 63;
    const int bi = blockIdx.y;   // output row tile
    const int bj = blockIdx.x;   // output col tile
    const int wr = wave >> 1, wc = wave & 1;

    f32x4 acc[4][4] = {};

    // staging: 512 chunks of 16B per tile; chunk c -> row c>>2, k-offset (c&3)*8
    const int c0  = wave * 64 + lane;
    const int r0  = c0 >> 2, ko0 = (c0 & 3) << 3;
    const int c1  = c0 + 256;
    const int r1  = c1 >> 2, ko1 = (c1 & 3) << 3;

    const bf16_t* gA0 = Xn + (long)(bi * 128 + r0) * KD + ko0;
    const bf16_t* gA1 = Xn + (long)(bi * 128 + r1) * KD + ko1;
    const bf16_t* gB0 = Xn + (long)(bj * 128 + r0) * KD + ko0;
    const bf16_t* gB1 = Xn + (long)(bj * 128 + r1) * KD + ko1;

    bf16_t* lA0 = &As[(wave * 64) * 8];
    bf16_t* lA1 = &As[(wave * 64 + 256) * 8];
    bf16_t* lB0 = &Bs[(wave * 64) * 8];
    bf16_t* lB1 = &Bs[(wave * 64 + 256) * 8];

    const int frow = lane & 15;         // fragment row (A) / col (B)
    const int kg   = (lane >> 4) << 3;  // k-group offset: 0,8,16,24

    for (int k0 = 0; k0 < KD; k0 += 32) {
        GLOAD_LDS16(gA0 + k0, lA0);
        GLOAD_LDS16(gA1 + k0, lA1);
        GLOAD_LDS16(gB0 + k0, lB0);
        GLOAD_LDS16(gB1 + k0, lB1);
        __syncthreads();  // compiler emits vmcnt(0) drain here

        bf16x8 a[4], b[4];
#pragma unroll
        for (int m = 0; m < 4; ++m)
            a[m] = *(const bf16x8*)&As[(wr * 64 + m * 16 + frow) * 32 + kg];
#pragma unroll
        for (int n = 0; n < 4; ++n)
            b[n] = *(const bf16x8*)&Bs[(wc * 64 + n * 16 + frow) * 32 + kg];
#pragma unroll
        for (int m = 0; m < 4; ++m)
#pragma unroll
            for (int n = 0; n < 4; ++n)
                acc[m][n] = __builtin_amdgcn_mfma_f32_16x16x32_bf16(
                    a[m], b[n], acc[m][n], 0, 0, 0);
        __syncthreads();
    }

    // epilogue: out[i][j][k] = sim*w[k] + b[k], float2 per sim element
    const float w0 = fcw[0], w1 = fcw[1];
    const float b0 = fcb[0], b1 = fcb[1];
    const int row0 = bi * 128 + wr * 64 + ((lane >> 4) << 2);
    const int col0 = bj * 128 + wc * 64 + (lane & 15);
#pragma unroll
    for (int m = 0; m < 4; ++m)
#pragma unroll
        for (int n = 0; n < 4; ++n) {
            const int col = col0 + n * 16;
#pragma unroll
            for (int r = 0; r < 4; ++r) {
                const long row = row0 + m * 16 + r;
                const float s = acc[m][n][r];
                float2 v = make_float2(fmaf(s, w0, b0), fmaf(s, w1, b1));
                *(float2*)&out[(row * BDIM + col) * 2] = v;
            }
        }
}

extern "C" void kernel_launch(void* const* d_in, const int* in_sizes, int n_in,
                              void* d_out, int out_size, void* d_ws, size_t ws_size,
                              hipStream_t stream) {
    const float* x   = (const float*)d_in[0];
    const float* fcw = (const float*)d_in[1];  // [w00, w10]
    const float* fcb = (const float*)d_in[2];  // [b0, b1]
    float* out = (float*)d_out;

    __hip_bfloat16* xn = (__hip_bfloat16*)d_ws;  // 4096*768*2B = 6.3 MB

    normalize_rows<<<BDIM, 256, 0, stream>>>(x, xn);

    dim3 grid(BDIM / 128, BDIM / 128);  // 32 x 32
    sim_gemm<<<grid, 256, 0, stream>>>((const bf16_t*)xn, fcw, fcb, out);
}